// Round 11
// baseline (370.240 us; speedup 1.0000x reference)
//
#include <hip/hip_runtime.h>
#include <stdint.h>

#define B_ 4
#define D_ 256
#define N_ 4096
#define K_ 8192
#define Q_ (B_*N_)   // 16384 queries

#define KSPLIT_ 4            // K-split; blockIdx&3 -> XCD-resident 2MB e-slice
#define KSLICE_ (K_/KSPLIT_) // 2048 codes per block
#define NCHUNK_ 64           // 32-code retire chunks
#define QTILE_ 256           // queries per block (4 waves x 64)

typedef __attribute__((ext_vector_type(8))) short bf16x8;
typedef __attribute__((ext_vector_type(16))) float f32x16;
typedef __attribute__((ext_vector_type(4))) unsigned short us4;

__device__ __forceinline__ unsigned short f32_to_bf16(float f) {
  unsigned u = __float_as_uint(f);
  unsigned r = 0x7FFFu + ((u >> 16) & 1u);
  return (unsigned short)((u + r) >> 16);
}
__device__ __forceinline__ float bf16_to_f32(unsigned short h) {
  return __uint_as_float(((unsigned)h) << 16);
}

// Fused prep (R10, kept): blocks [0,256) transpose x into xh/xl bf16 hi/lo;
// blocks [256,1280) split e + 0.5||e||^2 + keys init. All loads/stores
// vectorized (float4 / short4).
__global__ __launch_bounds__(512) void prep_kernel(
    const float* __restrict__ x, const float* __restrict__ e,
    unsigned short* __restrict__ xh, unsigned short* __restrict__ xl,
    unsigned short* __restrict__ eh, unsigned short* __restrict__ el,
    float* __restrict__ e2h, unsigned long long* __restrict__ keys) {
  __shared__ float tile[64][260];
  const int t = threadIdx.x;
  const int w = t >> 6;
  const int lam = t & 63;

  if (blockIdx.x < 256) {
    const int b = blockIdx.x >> 6;
    const int n0 = (blockIdx.x & 63) << 6;
#pragma unroll
    for (int p = 0; p < 4; ++p) {
      const int d = p * 64 + (t >> 3);
      const int f4 = t & 7;
      const float* src = x + (size_t)(b * D_ + d) * N_ + n0;
      float4 v1 = *(const float4*)(src + f4 * 4);
      float4 v2 = *(const float4*)(src + 32 + f4 * 4);
      tile[f4 * 4 + 0][d] = v1.x; tile[f4 * 4 + 1][d] = v1.y;
      tile[f4 * 4 + 2][d] = v1.z; tile[f4 * 4 + 3][d] = v1.w;
      tile[32 + f4 * 4 + 0][d] = v2.x; tile[32 + f4 * 4 + 1][d] = v2.y;
      tile[32 + f4 * 4 + 2][d] = v2.z; tile[32 + f4 * 4 + 3][d] = v2.w;
    }
    __syncthreads();
#pragma unroll
    for (int i = 0; i < 8; ++i) {
      const int q = w * 8 + i;
      float4 v = *(const float4*)&tile[q][lam * 4];
      unsigned short h0 = f32_to_bf16(v.x), h1 = f32_to_bf16(v.y);
      unsigned short h2 = f32_to_bf16(v.z), h3 = f32_to_bf16(v.w);
      us4 hv = {h0, h1, h2, h3};
      us4 lv = {f32_to_bf16(v.x - bf16_to_f32(h0)),
                f32_to_bf16(v.y - bf16_to_f32(h1)),
                f32_to_bf16(v.z - bf16_to_f32(h2)),
                f32_to_bf16(v.w - bf16_to_f32(h3))};
      const size_t qg = (size_t)b * N_ + n0 + q;
      *(us4*)(xh + qg * D_ + lam * 4) = hv;
      *(us4*)(xl + qg * D_ + lam * 4) = lv;
    }
  } else {
    const int k0 = ((int)blockIdx.x - 256) * 8;
    const int k = k0 + w;
    float4 v = *(const float4*)(e + (size_t)k * D_ + lam * 4);
    unsigned short h0 = f32_to_bf16(v.x), h1 = f32_to_bf16(v.y);
    unsigned short h2 = f32_to_bf16(v.z), h3 = f32_to_bf16(v.w);
    us4 hv = {h0, h1, h2, h3};
    us4 lv = {f32_to_bf16(v.x - bf16_to_f32(h0)),
              f32_to_bf16(v.y - bf16_to_f32(h1)),
              f32_to_bf16(v.z - bf16_to_f32(h2)),
              f32_to_bf16(v.w - bf16_to_f32(h3))};
    *(us4*)(eh + (size_t)k * D_ + lam * 4) = hv;
    *(us4*)(el + (size_t)k * D_ + lam * 4) = lv;
    float sq = v.x * v.x + v.y * v.y + v.z * v.z + v.w * v.w;
#pragma unroll
    for (int xm = 1; xm <= 32; xm <<= 1) sq += __shfl_xor(sq, xm, 64);
    if (lam == 0) e2h[k] = 0.5f * sq;
    if (t < 16) keys[(size_t)k0 * 2 + t] = ~0ull;
  }
}

// Main R11: DIRECT-FROM-L2 B-reads, zero LDS, zero barriers.
// R0-R10: the LDS-staged structure (DMA + vmcnt-drain barrier + ds_read) was
// pinned at 52-55% MfmaUtil under every scheduling variation; its LDS pipe
// floor (~85 B/cyc/CU) equals the MFMA floor — a knife-edge no schedule fixed.
// The e-slice (2 MB/block) is L2-RESIDENT per XCD (ksl=blockIdx&3 mapping), so
// staging it through LDS is pure overhead (catalog common-mistake #7).
// New: 4 independent waves/CU (1/SIMD), M=64 queries/wave (A = 256 AGPRs at
// the 512-reg budget, launch_bounds(256,1)); per ks-step one 32B B-pair read
// straight from L1/L2 feeds 6 MFMAs (193 cyc own cover vs ~200 cyc L2
// latency) with a depth-2 rotation (~390 cyc lookahead). Demand ~42 B/cyc/CU
// vs ~56-64 available. Addressing is base+imm (swizzle gone). No syncs at all.
__global__ __launch_bounds__(256, 1) void vq_main_kernel(
    const unsigned short* __restrict__ xh, const unsigned short* __restrict__ xl,
    const unsigned short* __restrict__ eh, const unsigned short* __restrict__ el,
    const float* __restrict__ e2h, unsigned long long* __restrict__ keys) {
  const int tid = threadIdx.x;
  const int w = tid >> 6;       // wave 0..3
  const int lane = tid & 63;
  const int l = lane & 31;      // code col / query row
  const int hi = lane >> 5;     // k-group half

  const int qt = blockIdx.x >> 2;
  const int ksl = blockIdx.x & 3;
  const int kbase = ksl * KSLICE_;
  const int qw = qt * QTILE_ + w * 64;  // 64 queries per wave (2 M-tiles)

  // Persistent A fragments: 2 tiles x 32 q x 256 d, hi+lo = 256 regs (AGPR).
  bf16x8 ah0[16], al0[16], ah1[16], al1[16];
  {
    const unsigned short* p0h = xh + (size_t)(qw + l) * D_ + hi * 8;
    const unsigned short* p0l = xl + (size_t)(qw + l) * D_ + hi * 8;
    const unsigned short* p1h = xh + (size_t)(qw + 32 + l) * D_ + hi * 8;
    const unsigned short* p1l = xl + (size_t)(qw + 32 + l) * D_ + hi * 8;
#pragma unroll
    for (int kc16 = 0; kc16 < 16; ++kc16) {
      ah0[kc16] = *(const bf16x8*)(p0h + kc16 * 16);
      al0[kc16] = *(const bf16x8*)(p0l + kc16 * 16);
      ah1[kc16] = *(const bf16x8*)(p1h + kc16 * 16);
      al1[kc16] = *(const bf16x8*)(p1l + kc16 * 16);
    }
  }

  float rminv0[16], rminv1[16];
  unsigned rmp0[4], rmp1[4];  // packed 8-bit chunk ids
#pragma unroll
  for (int r = 0; r < 16; ++r) { rminv0[r] = __builtin_inff(); rminv1[r] = __builtin_inff(); }
#pragma unroll
  for (int i = 0; i < 4; ++i) { rmp0[i] = 0u; rmp1[i] = 0u; }

  // Per-lane B base: row kbase+l, d-offset hi*8. Chunk ch adds ch*32 rows;
  // ks adds 16 shorts (imm-foldable).
  const unsigned short* pbh = eh + (size_t)(kbase + l) * D_ + hi * 8;
  const unsigned short* pbl = el + (size_t)(kbase + l) * D_ + hi * 8;

#pragma unroll 1
  for (int ch = 0; ch < NCHUNK_; ++ch) {
    const unsigned short* ph = pbh + (size_t)ch * 32 * D_;
    const unsigned short* pl = pbl + (size_t)ch * 32 * D_;
    const float e2v = e2h[kbase + ch * 32 + l];

    f32x16 acc0, acc1;
#pragma unroll
    for (int r = 0; r < 16; ++r) { acc0[r] = 0.f; acc1[r] = 0.f; }

    // depth-2 rotation: loads for ks+2 issue before MFMAs of ks
    bf16x8 cbh = *(const bf16x8*)(ph);
    bf16x8 cbl = *(const bf16x8*)(pl);
    bf16x8 nbh = *(const bf16x8*)(ph + 16);
    bf16x8 nbl = *(const bf16x8*)(pl + 16);
#pragma unroll
    for (int ks = 0; ks < 16; ++ks) {
      const bf16x8 ubh = cbh, ubl = cbl;
      cbh = nbh; cbl = nbl;
      if (ks + 2 < 16) {
        nbh = *(const bf16x8*)(ph + (ks + 2) * 16);
        nbl = *(const bf16x8*)(pl + (ks + 2) * 16);
      }
      // one 32B B-pair feeds 6 MFMAs; acc0/acc1 alternate (dep dist 2)
      acc0 = __builtin_amdgcn_mfma_f32_32x32x16_bf16(ah0[ks], ubh, acc0, 0, 0, 0);
      acc1 = __builtin_amdgcn_mfma_f32_32x32x16_bf16(ah1[ks], ubh, acc1, 0, 0, 0);
      acc0 = __builtin_amdgcn_mfma_f32_32x32x16_bf16(ah0[ks], ubl, acc0, 0, 0, 0);
      acc1 = __builtin_amdgcn_mfma_f32_32x32x16_bf16(ah1[ks], ubl, acc1, 0, 0, 0);
      acc0 = __builtin_amdgcn_mfma_f32_32x32x16_bf16(al0[ks], ubh, acc0, 0, 0, 0);
      acc1 = __builtin_amdgcn_mfma_f32_32x32x16_bf16(al1[ks], ubh, acc1, 0, 0, 0);
    }

    const unsigned vc = (unsigned)ch;
#pragma unroll
    for (int r = 0; r < 16; ++r) {
      const unsigned sh = (r & 3) * 8;
      float dv0 = e2v - acc0[r];
      bool b0 = dv0 < rminv0[r];
      rminv0[r] = b0 ? dv0 : rminv0[r];
      unsigned np0 = (rmp0[r >> 2] & ~(0xFFu << sh)) | (vc << sh);
      rmp0[r >> 2] = b0 ? np0 : rmp0[r >> 2];
      float dv1 = e2v - acc1[r];
      bool b1 = dv1 < rminv1[r];
      rminv1[r] = b1 ? dv1 : rminv1[r];
      unsigned np1 = (rmp1[r >> 2] & ~(0xFFu << sh)) | (vc << sh);
      rmp1[r >> 2] = b1 ? np1 : rmp1[r >> 2];
    }
  }

  // Reduce over the 32 code-columns within each half-wave, then cross-block
  // merge via packed (sortable-float<<32 | idx) u64 atomicMin. Two tiles.
#pragma unroll
  for (int r = 0; r < 16; ++r) {
    const int m = (r & 3) + 8 * (r >> 2) + 4 * hi;  // C/D row mapping (m74/m101)
    const unsigned sh = (r & 3) * 8;
    {
      float bv = rminv0[r];
      int bi = kbase + (int)((rmp0[r >> 2] >> sh) & 0xFFu) * 32 + l;
#pragma unroll
      for (int xm = 1; xm <= 16; xm <<= 1) {
        float ov = __shfl_xor(bv, xm, 64);
        int oi = __shfl_xor(bi, xm, 64);
        if (ov < bv || (ov == bv && oi < bi)) { bv = ov; bi = oi; }
      }
      if (l == 0) {
        unsigned su = __float_as_uint(bv);
        su ^= (unsigned)(((int)su >> 31) | 0x80000000u);
        unsigned long long key = ((unsigned long long)su << 32) | (unsigned)bi;
        atomicMin(keys + (qw + m), key);
      }
    }
    {
      float bv = rminv1[r];
      int bi = kbase + (int)((rmp1[r >> 2] >> sh) & 0xFFu) * 32 + l;
#pragma unroll
      for (int xm = 1; xm <= 16; xm <<= 1) {
        float ov = __shfl_xor(bv, xm, 64);
        int oi = __shfl_xor(bi, xm, 64);
        if (ov < bv || (ov == bv && oi < bi)) { bv = ov; bi = oi; }
      }
      if (l == 0) {
        unsigned su = __float_as_uint(bv);
        su ^= (unsigned)(((int)su >> 31) | 0x80000000u);
        unsigned long long key = ((unsigned long long)su << 32) | (unsigned)bi;
        atomicMin(keys + (qw + 32 + m), key);
      }
    }
  }
}

// Decode (R10, kept): stage 32 full e-rows via float4, 2 barriers,
// float4 output stores.
__global__ __launch_bounds__(256) void decode_kernel(
    const unsigned long long* __restrict__ keys,
    const float* __restrict__ e, float* __restrict__ out) {
  __shared__ float tile[32][260];
  __shared__ int codes[32];
  const int t = threadIdx.x;
  const int b = blockIdx.y;
  const int n0 = blockIdx.x * 32;
  const int w = t >> 6, lam = t & 63;
  if (t < 32)
    codes[t] = (int)(keys[(size_t)b * N_ + n0 + t] & 0xFFFFFFFFull);
  __syncthreads();
#pragma unroll
  for (int i = 0; i < 8; ++i) {
    const int row = w * 8 + i;
    float4 ev = *(const float4*)(e + (size_t)codes[row] * D_ + lam * 4);
    *(float4*)&tile[row][lam * 4] = ev;
  }
  __syncthreads();
#pragma unroll
  for (int iter = 0; iter < 8; ++iter) {
    const int d = iter * 32 + (t >> 3);
    const int nc = (t & 7) * 4;
    float4 ov = {tile[nc][d], tile[nc + 1][d], tile[nc + 2][d], tile[nc + 3][d]};
    *(float4*)(out + (size_t)(b * D_ + d) * N_ + n0 + nc) = ov;
  }
}

extern "C" void kernel_launch(void* const* d_in, const int* in_sizes, int n_in,
                              void* d_out, int out_size, void* d_ws, size_t ws_size,
                              hipStream_t stream) {
  const float* x = (const float*)d_in[0];
  const float* e = (const float*)d_in[1];
  float* out = (float*)d_out;

  // workspace layout (~24.2 MB)
  char* wksp = (char*)d_ws;
  unsigned short* xh = (unsigned short*)wksp;                   // 8 MB
  unsigned short* xl = xh + (size_t)Q_ * D_;                    // 8 MB
  unsigned short* eh = xl + (size_t)Q_ * D_;                    // 4 MB
  unsigned short* el = eh + (size_t)K_ * D_;                    // 4 MB
  float* e2h = (float*)(el + (size_t)K_ * D_);                  // 32 KB
  unsigned long long* keys = (unsigned long long*)(e2h + K_);   // 128 KB

  prep_kernel<<<1280, 512, 0, stream>>>(x, e, xh, xl, eh, el, e2h, keys);
  vq_main_kernel<<<(Q_ / QTILE_) * KSPLIT_, 256, 0, stream>>>(xh, xl, eh, el, e2h, keys);
  decode_kernel<<<dim3(N_ / 32, B_), 256, 0, stream>>>(keys, e, out);
}

// Round 12
// 264.312 us; speedup vs baseline: 1.4008x; 1.4008x over previous
//
#include <hip/hip_runtime.h>
#include <stdint.h>

#define B_ 4
#define D_ 256
#define N_ 4096
#define K_ 8192
#define Q_ (B_*N_)   // 16384 queries

#define KSPLIT_ 4            // K-split; blockIdx&3 + XCD round-robin -> each
#define KSLICE_ (K_/KSPLIT_) //   XCD's L2 holds one 2MB eh + 1MB el2 slice
#define CHUNK_ 64            // codes per chunk (2 x 32-code MFMA sub-tiles)
#define NCHUNK_ (KSLICE_/CHUNK_) // 32 chunks
#define QTILE_ 256           // queries per block (8 waves x 32)

typedef __attribute__((ext_vector_type(8))) short bf16x8;
typedef __attribute__((ext_vector_type(16))) float f32x16;
typedef __attribute__((ext_vector_type(4))) unsigned short us4;

__device__ __forceinline__ unsigned short f32_to_bf16(float f) {
  unsigned u = __float_as_uint(f);
  unsigned r = 0x7FFFu + ((u >> 16) & 1u);
  return (unsigned short)((u + r) >> 16);
}
__device__ __forceinline__ float bf16_to_f32(unsigned short h) {
  return __uint_as_float(((unsigned)h) << 16);
}

// async global->LDS, 16B per lane; LDS dest is wave-uniform base + lane*16
__device__ __forceinline__ void gl_lds16(const void* g, void* l) {
  __builtin_amdgcn_global_load_lds(
      (const __attribute__((address_space(1))) unsigned int*)g,
      (__attribute__((address_space(3))) unsigned int*)l, 16, 0, 0);
}

// Fused prep: blocks [0,256) transpose x into xh/xl bf16 hi/lo (vectorized).
// Blocks [256,1280): e-role — eh flat [k][d] (DMA source), el2 in PACKED
// FRAGMENT-MAJOR layout so vq's bl global reads are fully coalesced:
//   el2[(((k>>5)*16 + d/16)*32 + (k&31))*16 + ((d>>3)&1)*8 + (d&7)]
// (a wave's fragment = one contiguous 1KB segment). Plus 0.5||e||^2, keys.
__global__ __launch_bounds__(512) void prep_kernel(
    const float* __restrict__ x, const float* __restrict__ e,
    unsigned short* __restrict__ xh, unsigned short* __restrict__ xl,
    unsigned short* __restrict__ eh, unsigned short* __restrict__ el2,
    float* __restrict__ e2h, unsigned long long* __restrict__ keys) {
  __shared__ float tile[64][260];
  const int t = threadIdx.x;
  const int w = t >> 6;
  const int lam = t & 63;

  if (blockIdx.x < 256) {
    const int b = blockIdx.x >> 6;
    const int n0 = (blockIdx.x & 63) << 6;
#pragma unroll
    for (int p = 0; p < 4; ++p) {
      const int d = p * 64 + (t >> 3);
      const int f4 = t & 7;
      const float* src = x + (size_t)(b * D_ + d) * N_ + n0;
      float4 v1 = *(const float4*)(src + f4 * 4);
      float4 v2 = *(const float4*)(src + 32 + f4 * 4);
      tile[f4 * 4 + 0][d] = v1.x; tile[f4 * 4 + 1][d] = v1.y;
      tile[f4 * 4 + 2][d] = v1.z; tile[f4 * 4 + 3][d] = v1.w;
      tile[32 + f4 * 4 + 0][d] = v2.x; tile[32 + f4 * 4 + 1][d] = v2.y;
      tile[32 + f4 * 4 + 2][d] = v2.z; tile[32 + f4 * 4 + 3][d] = v2.w;
    }
    __syncthreads();
#pragma unroll
    for (int i = 0; i < 8; ++i) {
      const int q = w * 8 + i;
      float4 v = *(const float4*)&tile[q][lam * 4];
      unsigned short h0 = f32_to_bf16(v.x), h1 = f32_to_bf16(v.y);
      unsigned short h2 = f32_to_bf16(v.z), h3 = f32_to_bf16(v.w);
      us4 hv = {h0, h1, h2, h3};
      us4 lv = {f32_to_bf16(v.x - bf16_to_f32(h0)),
                f32_to_bf16(v.y - bf16_to_f32(h1)),
                f32_to_bf16(v.z - bf16_to_f32(h2)),
                f32_to_bf16(v.w - bf16_to_f32(h3))};
      const size_t qg = (size_t)b * N_ + n0 + q;
      *(us4*)(xh + qg * D_ + lam * 4) = hv;
      *(us4*)(xl + qg * D_ + lam * 4) = lv;
    }
  } else {
    const int k0 = ((int)blockIdx.x - 256) * 8;
    const int k = k0 + w;
    float4 v = *(const float4*)(e + (size_t)k * D_ + lam * 4);
    unsigned short h0 = f32_to_bf16(v.x), h1 = f32_to_bf16(v.y);
    unsigned short h2 = f32_to_bf16(v.z), h3 = f32_to_bf16(v.w);
    us4 hv = {h0, h1, h2, h3};
    us4 lv = {f32_to_bf16(v.x - bf16_to_f32(h0)),
              f32_to_bf16(v.y - bf16_to_f32(h1)),
              f32_to_bf16(v.z - bf16_to_f32(h2)),
              f32_to_bf16(v.w - bf16_to_f32(h3))};
    *(us4*)(eh + (size_t)k * D_ + lam * 4) = hv;
    const int d = lam * 4;
    const size_t paddr =
        ((size_t)((k >> 5) * 16 + (d >> 4)) * 32 + (k & 31)) * 16 +
        ((d >> 3) & 1) * 8 + (d & 7);
    *(us4*)(el2 + paddr) = lv;
    float sq = v.x * v.x + v.y * v.y + v.z * v.z + v.w * v.w;
#pragma unroll
    for (int xm = 1; xm <= 32; xm <<= 1) sq += __shfl_xor(sq, xm, 64);
    if (lam == 0) e2h[k] = 0.5f * sq;
    if (t < 16) keys[(size_t)k0 * 2 + t] = ~0ull;
  }
}

// Main R12: HYBRID B-FEED. R0-R10 invariant explained: at the MFMA floor the
// all-LDS feed needs ~85 B/cyc/CU == the measured LDS ceiling — two exactly
// balanced pipes, and no schedule sustains 100% on both. Split the feed:
// bh via DMA->LDS->ds_read (half the old LDS traffic, 3072 cyc/chunk/CU);
// bl via COALESCED global reads from the packed, XCD-L2-resident el2 (1KB
// per wave-instr, ~1500 cyc/chunk/CU on the VMEM pipe; R11's failure was
// the 32-line scatter, fixed by prep's fragment-major packing). MFMA
// (6144 cyc/SIMD/chunk) is now the sole floor. Frame otherwise = R10 best:
// 8 waves x 32 q, 2/SIMD, CHUNK=64, depth-2/3 read rotation, rmp packing.
__global__ __launch_bounds__(512, 2) void vq_main_kernel(
    const unsigned short* __restrict__ xh, const unsigned short* __restrict__ xl,
    const unsigned short* __restrict__ eh, const unsigned short* __restrict__ el2,
    const float* __restrict__ e2h, unsigned long long* __restrict__ keys) {
  // bh only: [buf][code*256 swizzled runs], 64 KB, dense (DMA-compatible).
  // 16B-slot s of code row c holds run g = s ^ (c&31).
  __shared__ __attribute__((aligned(16))) unsigned short Bs[2][CHUNK_ * 256];

  const int tid = threadIdx.x;
  const int w = tid >> 6;       // wave 0..7
  const int lane = tid & 63;
  const int l = lane & 31;      // code col / query row
  const int hi = lane >> 5;     // k-group half

  const int qt = blockIdx.x >> 2;
  const int ksl = blockIdx.x & 3;
  const int q0 = qt * QTILE_;
  const int kbase = ksl * KSLICE_;
  const int qw = q0 + w * 32;

  // Persistent A fragments: 32 q x 256 d, hi+lo = 128 regs (AGPRs).
  bf16x8 ah[16], al[16];
  {
    const unsigned short* pa = xh + (size_t)(qw + l) * D_ + hi * 8;
    const unsigned short* pb = xl + (size_t)(qw + l) * D_ + hi * 8;
#pragma unroll
    for (int kc16 = 0; kc16 < 16; ++kc16) {
      ah[kc16] = *(const bf16x8*)(pa + kc16 * 16);
      al[kc16] = *(const bf16x8*)(pb + kc16 * 16);
    }
  }

  float rminv[16];
  unsigned rmp[4];  // 16 x 8-bit packed chunk-subtile codes (vc = ch*2+st)
#pragma unroll
  for (int r = 0; r < 16; ++r) rminv[r] = __builtin_inff();
#pragma unroll
  for (int i = 0; i < 4; ++i) rmp[i] = 0u;

  // Stage chunk ch's bh (64 codes) into buf: wave w loads codes [w*8,w*8+8).
  // 4 gl_lds per wave per chunk (was 8 with el staged too).
  auto stage = [&](int ch, int buf) {
    const int kc = kbase + ch * CHUNK_;
#pragma unroll
    for (int p = 0; p < 4; ++p) {
      const int c0 = w * 8 + p * 2;
      const int c = c0 + hi;
      const int g = l ^ (c & 31);
      const size_t srcoff = (size_t)(kc + c) * D_ + g * 8;
      gl_lds16(eh + srcoff, &Bs[buf][c0 * 256]);
    }
  };

  // Per-lane bl base in packed el2 (lane's 16B slot of the 1KB fragment).
  const unsigned short* pbl = el2 + (size_t)kbase * 256 + l * 16 + hi * 8;
  // fragment (ch,kk): wave-uniform offset ((ch*2+st)*16+ks)*512 shorts
#define BL(kk) (*(const bf16x8*)(pbl + \
    (size_t)(((ch * 2 + ((kk) >> 4)) * 16 + ((kk) & 15)) * 512)))
  // bh LDS read: subtile st=kk>>4 (row 32*st+l), swizzled slot
#define RD(kk) (*(const bf16x8*)&Bs[buf][(((kk) >> 4) * 32 + l) * 256 + \
    (((((kk) & 15) * 2 + hi) ^ l) * 8)])

  stage(0, 0);

#pragma unroll 1
  for (int ch = 0; ch < NCHUNK_; ++ch) {
    const int buf = ch & 1;
    __syncthreads();                    // drains DMA for chunk ch
    if (ch + 1 < NCHUNK_) stage(ch + 1, buf ^ 1);
    const int kc = kbase + ch * CHUNK_;
    const float e2v0 = e2h[kc + l];
    const float e2v1 = e2h[kc + 32 + l];

    f32x16 acc0, acc1;
#pragma unroll
    for (int r = 0; r < 16; ++r) { acc0[r] = 0.f; acc1[r] = 0.f; }

    // read rotation: bh depth-2 (LDS ~40cyc), bl depth-3 (L1/L2 ~150cyc)
    bf16x8 cbh = RD(0), nbh = RD(1);
    bf16x8 cbl = BL(0), nbl = BL(1), mbl = BL(2);
#pragma unroll
    for (int kk = 0; kk < 32; ++kk) {
      const bf16x8 ubh = cbh, ubl = cbl;
      cbh = nbh; if (kk + 2 < 32) nbh = RD(kk + 2);
      cbl = nbl; nbl = mbl; if (kk + 3 < 32) mbl = BL(kk + 3);
      const int ks = kk & 15;
      if (kk < 16) {
        acc0 = __builtin_amdgcn_mfma_f32_32x32x16_bf16(ah[ks], ubh, acc0, 0, 0, 0);
        acc0 = __builtin_amdgcn_mfma_f32_32x32x16_bf16(ah[ks], ubl, acc0, 0, 0, 0);
        acc0 = __builtin_amdgcn_mfma_f32_32x32x16_bf16(al[ks], ubh, acc0, 0, 0, 0);
      } else {
        acc1 = __builtin_amdgcn_mfma_f32_32x32x16_bf16(ah[ks], ubh, acc1, 0, 0, 0);
        acc1 = __builtin_amdgcn_mfma_f32_32x32x16_bf16(ah[ks], ubl, acc1, 0, 0, 0);
        acc1 = __builtin_amdgcn_mfma_f32_32x32x16_bf16(al[ks], ubh, acc1, 0, 0, 0);
      }
      if (kk == 15) {  // retire subtile 0
        const unsigned vc = (unsigned)(ch * 2 + 0);
#pragma unroll
        for (int r = 0; r < 16; ++r) {
          float dv = e2v0 - acc0[r];
          bool better = dv < rminv[r];
          rminv[r] = better ? dv : rminv[r];
          const unsigned sh = (r & 3) * 8;
          unsigned np = (rmp[r >> 2] & ~(0xFFu << sh)) | (vc << sh);
          rmp[r >> 2] = better ? np : rmp[r >> 2];
        }
      }
    }
#undef RD
#undef BL
    {  // retire subtile 1
      const unsigned vc = (unsigned)(ch * 2 + 1);
#pragma unroll
      for (int r = 0; r < 16; ++r) {
        float dv = e2v1 - acc1[r];
        bool better = dv < rminv[r];
        rminv[r] = better ? dv : rminv[r];
        const unsigned sh = (r & 3) * 8;
        unsigned np = (rmp[r >> 2] & ~(0xFFu << sh)) | (vc << sh);
        rmp[r >> 2] = better ? np : rmp[r >> 2];
      }
    }
  }

  // Reduce over the 32 code-columns within each half-wave, then cross-block
  // merge via packed (sortable-float<<32 | idx) u64 atomicMin.
#pragma unroll
  for (int r = 0; r < 16; ++r) {
    float bv = rminv[r];
    const unsigned sh = (r & 3) * 8;
    int bi = kbase + (int)((rmp[r >> 2] >> sh) & 0xFFu) * 32 + l;
#pragma unroll
    for (int xm = 1; xm <= 16; xm <<= 1) {
      float ov = __shfl_xor(bv, xm, 64);
      int oi = __shfl_xor(bi, xm, 64);
      if (ov < bv || (ov == bv && oi < bi)) { bv = ov; bi = oi; }
    }
    if (l == 0) {
      const int m = (r & 3) + 8 * (r >> 2) + 4 * hi;  // C/D row mapping (m74/m101)
      const int qq = qw + m;
      unsigned su = __float_as_uint(bv);
      su ^= (unsigned)(((int)su >> 31) | 0x80000000u);
      unsigned long long key = ((unsigned long long)su << 32) | (unsigned)bi;
      atomicMin(keys + qq, key);
    }
  }
}

// Decode (R10, kept): stage 32 full e-rows via float4, 2 barriers,
// float4 output stores.
__global__ __launch_bounds__(256) void decode_kernel(
    const unsigned long long* __restrict__ keys,
    const float* __restrict__ e, float* __restrict__ out) {
  __shared__ float tile[32][260];
  __shared__ int codes[32];
  const int t = threadIdx.x;
  const int b = blockIdx.y;
  const int n0 = blockIdx.x * 32;
  const int w = t >> 6, lam = t & 63;
  if (t < 32)
    codes[t] = (int)(keys[(size_t)b * N_ + n0 + t] & 0xFFFFFFFFull);
  __syncthreads();
#pragma unroll
  for (int i = 0; i < 8; ++i) {
    const int row = w * 8 + i;
    float4 ev = *(const float4*)(e + (size_t)codes[row] * D_ + lam * 4);
    *(float4*)&tile[row][lam * 4] = ev;
  }
  __syncthreads();
#pragma unroll
  for (int iter = 0; iter < 8; ++iter) {
    const int d = iter * 32 + (t >> 3);
    const int nc = (t & 7) * 4;
    float4 ov = {tile[nc][d], tile[nc + 1][d], tile[nc + 2][d], tile[nc + 3][d]};
    *(float4*)(out + (size_t)(b * D_ + d) * N_ + n0 + nc) = ov;
  }
}

extern "C" void kernel_launch(void* const* d_in, const int* in_sizes, int n_in,
                              void* d_out, int out_size, void* d_ws, size_t ws_size,
                              hipStream_t stream) {
  const float* x = (const float*)d_in[0];
  const float* e = (const float*)d_in[1];
  float* out = (float*)d_out;

  // workspace layout (~24.2 MB)
  char* wksp = (char*)d_ws;
  unsigned short* xh = (unsigned short*)wksp;                   // 8 MB
  unsigned short* xl = xh + (size_t)Q_ * D_;                    // 8 MB
  unsigned short* eh = xl + (size_t)Q_ * D_;                    // 4 MB
  unsigned short* el2 = eh + (size_t)K_ * D_;                   // 4 MB (packed)
  float* e2h = (float*)(el2 + (size_t)K_ * D_);                 // 32 KB
  unsigned long long* keys = (unsigned long long*)(e2h + K_);   // 128 KB

  prep_kernel<<<1280, 512, 0, stream>>>(x, e, xh, xl, eh, el2, e2h, keys);
  vq_main_kernel<<<(Q_ / QTILE_) * KSPLIT_, 512, 0, stream>>>(xh, xl, eh, el2, e2h, keys);
  decode_kernel<<<dim3(N_ / 32, B_), 256, 0, stream>>>(keys, e, out);
}